// Round 16
// baseline (971.123 us; speedup 1.0000x reference)
//
#include <hip/hip_runtime.h>
#include <hip/hip_bf16.h>
#include <math.h>

typedef __bf16 bf16x8 __attribute__((ext_vector_type(8)));
typedef float f32x4 __attribute__((ext_vector_type(4)));
typedef float f32x2 __attribute__((ext_vector_type(2)));

#define NPTS 8192
#define SGRP 512
#define KNBR 32
#define CCH 384
#define LDSP 392   // padded ushort row stride for [l][c] LDS tiles

static __device__ __forceinline__ unsigned short f2b(float f) {
  union { float f; unsigned u; } v; v.f = f;
  return (unsigned short)((v.u + 0x7fffu + ((v.u >> 16) & 1u)) >> 16);
}
static __device__ __forceinline__ float b2f(unsigned short u) {
  union { unsigned u; float f; } v; v.u = ((unsigned)u) << 16;
  return v.f;
}
static __device__ __forceinline__ unsigned pk2(float a, float b) {
  return (unsigned)f2b(a) | ((unsigned)f2b(b) << 16);
}

// fmax/fmin with DPP-shifted self. Identity for shifted-in lanes:
// max: 0 (distances >= 0); min: +inf.
#define DPPMAX(v, ctrl) \
  fmaxf((v), __int_as_float(__builtin_amdgcn_update_dpp(0, __float_as_int(v), (ctrl), 0xf, 0xf, false)))
#define DPPMIN(v, ctrl) \
  fminf((v), __int_as_float(__builtin_amdgcn_update_dpp(0x7f800000, __float_as_int(v), (ctrl), 0xf, 0xf, false)))

struct FoldArgs {
  const float *W, *b, *g, *bb;
  unsigned short* Wd;
  float* bd;
};

// ---------------- FPS v13 + fused folds/psq (fps path byte-identical to r15) ----
// Blocks 0..7: FPS per batch (478us proven path). Blocks 8..23: bn-fold of the
// four 384x384 weight sets (block k: set k>>2, row quarter k&3) + t-net fold on
// block 8 -- these previously ran as 2 serialized launches before fps; now they
// run on idle CUs during fps. Blocks 24..31: psq[b][p] = (x^2+y^2)+z^2 per
// batch, contract-off (bit-identical to knn's old in-kernel expression).
// 96KB LDS = coord lookup + allocator pin for the fps blocks (prevents the
// 64-VGPR-budget spill -- DO NOT SHRINK xs/ys/zs).
__global__ __launch_bounds__(1024)
void fps_fold_kernel(const float* __restrict__ xyz, int* __restrict__ cIdx,
                     FoldArgs fa0, FoldArgs fa1, FoldArgs fa2, FoldArgs fa3,
                     const float* __restrict__ Wt, const float* __restrict__ bt,
                     const float* __restrict__ gt, const float* __restrict__ bbt,
                     float* __restrict__ WtF, float* __restrict__ btF,
                     float* __restrict__ psq) {
  #pragma clang fp contract(off)
  __shared__ float xs[NPTS], ys[NPTS], zs[NPTS];   // 96KB
  __shared__ float slotV[2][16];
  __shared__ unsigned slotI[2][16];
  const int blk = blockIdx.x;

  if (blk >= 8) {
    if (blk < 24) {   // ---- weight folds ----
      const int k = blk - 8;
      FoldArgs a = ((k >> 2) == 0) ? fa0 : ((k >> 2) == 1) ? fa1 : ((k >> 2) == 2) ? fa2 : fa3;
      const int q = k & 3;
      for (int i = threadIdx.x; i < 96 * CCH; i += 1024) {
        int r = i / CCH, c = i - r * CCH;
        int o = q * 96 + r;
        float sc = a.g[o] / sqrtf(1.0f + 1e-5f);
        a.Wd[o * CCH + c] = f2b(a.W[o * CCH + c] * sc);
      }
      if (q == 0) {
        for (int o = threadIdx.x; o < CCH; o += 1024) {
          float sc = a.g[o] / sqrtf(1.0f + 1e-5f);
          a.bd[o] = a.b[o] * sc + a.bb[o];
        }
      }
      if (k == 0) {   // t-net fold (f32)
        for (int i = threadIdx.x; i < CCH * 6; i += 1024) {
          int o = i / 6;
          float sc = gt[o] / sqrtf(1.0f + 1e-5f);
          WtF[i] = Wt[i] * sc;
        }
        for (int o = threadIdx.x; o < CCH; o += 1024) {
          float sc = gt[o] / sqrtf(1.0f + 1e-5f);
          btF[o] = bt[o] * sc + bbt[o];
        }
      }
    } else {          // ---- psq precompute (blocks 24..31, one batch each) ----
      const int bb_ = blk - 24;
      const float* xb2 = xyz + (size_t)bb_ * NPTS * 3;
      for (int i = threadIdx.x; i < NPTS; i += 1024) {
        float x = xb2[i * 3], y = xb2[i * 3 + 1], z = xb2[i * 3 + 2];
        psq[(size_t)bb_ * NPTS + i] = (x * x + y * y) + z * z;   // contract off
      }
    }
    return;
  }

  // ---- FPS path (blocks 0..7), identical to r15's proven 478us kernel ----
  const int tid = threadIdx.x, lane = tid & 63, wid = tid >> 6;   // wid 0..15
  const int b = blk;
  const float* xb = xyz + (size_t)b * NPTS * 3;

  f32x2 X2[4], Y2[4], Z2[4], D2[4];
  {
    const float4* s = (const float4*)xb + tid * 6;
    float4 t0 = s[0], t1 = s[1], t2 = s[2], t3 = s[3], t4 = s[4], t5 = s[5];
    X2[0] = (f32x2){t0.x, t0.w}; Y2[0] = (f32x2){t0.y, t1.x}; Z2[0] = (f32x2){t0.z, t1.y};
    X2[1] = (f32x2){t1.z, t2.y}; Y2[1] = (f32x2){t1.w, t2.z}; Z2[1] = (f32x2){t2.x, t2.w};
    X2[2] = (f32x2){t3.x, t3.w}; Y2[2] = (f32x2){t3.y, t4.x}; Z2[2] = (f32x2){t3.z, t4.y};
    X2[3] = (f32x2){t4.z, t5.y}; Y2[3] = (f32x2){t4.w, t5.z}; Z2[3] = (f32x2){t5.x, t5.w};
  }
  #pragma unroll
  for (int j = 0; j < 4; ++j) {
    int p = tid * 8 + j * 2;
    xs[p] = X2[j].x; ys[p] = Y2[j].x; zs[p] = Z2[j].x;
    xs[p + 1] = X2[j].y; ys[p + 1] = Y2[j].y; zs[p + 1] = Z2[j].y;
    D2[j] = (f32x2){__builtin_inff(), __builtin_inff()};
  }
  if (tid == 0) cIdx[b * SGRP] = 0;
  __syncthreads();
  float cx = xs[0], cy = ys[0], cz = zs[0];
  const int tbase = tid * 8;

  for (int step = 1; step < SGRP; ++step) {
    const int par = step & 1;
    const f32x2 cxv = (f32x2){cx, cx}, cyv = (f32x2){cy, cy}, czv = (f32x2){cz, cz};
    // packed dist update
    #pragma unroll
    for (int j = 0; j < 4; ++j) {
      f32x2 dx = X2[j] - cxv, dy = Y2[j] - cyv, dz = Z2[j] - czv;
      f32x2 d = (dx * dx + dy * dy) + dz * dz;   // contract off: numpy ulp-exact
      D2[j] = __builtin_elementwise_min(D2[j], d);
    }
    // value tree-max (v_max3-fusable triples), then index by equality scan
    float bv;
    {
      float a = fmaxf(fmaxf(D2[0].x, D2[0].y), D2[1].x);
      float c = fmaxf(fmaxf(D2[1].y, D2[2].x), D2[2].y);
      float e = fmaxf(fmaxf(D2[3].x, D2[3].y), a);
      bv = fmaxf(c, e);
    }
    int bi = tbase + 7;                          // descending j: lowest j wins
    bi = (D2[3].x == bv) ? tbase + 6 : bi;
    bi = (D2[2].y == bv) ? tbase + 5 : bi;
    bi = (D2[2].x == bv) ? tbase + 4 : bi;
    bi = (D2[1].y == bv) ? tbase + 3 : bi;
    bi = (D2[1].x == bv) ? tbase + 2 : bi;
    bi = (D2[0].y == bv) ? tbase + 1 : bi;
    bi = (D2[0].x == bv) ? tbase + 0 : bi;
    // wave max (value only), pure VALU
    float m = bv;
    m = DPPMAX(m, 0x111); m = DPPMAX(m, 0x112); m = DPPMAX(m, 0x114);
    m = DPPMAX(m, 0x118); m = DPPMAX(m, 0x142); m = DPPMAX(m, 0x143);
    float wmax = __uint_as_float(__builtin_amdgcn_readlane(__float_as_uint(m), 63));
    unsigned long long msk = __ballot(bv == wmax);
    int srcLane = (int)__builtin_ctzll(msk);          // lowest lane == lowest index
    unsigned wbi = (unsigned)__builtin_amdgcn_readlane(bi, srcLane);
    if (lane == 0) { slotV[par][wid] = wmax; slotI[par][wid] = wbi; }
    __syncthreads();   // the only barrier per step
    // in-register 16-slot combine: lane l holds slot l&15 (broadcast reads)
    float sv = slotV[par][lane & 15];
    unsigned si = slotI[par][lane & 15];
    float g = sv;
    g = DPPMAX(g, 0x111); g = DPPMAX(g, 0x112); g = DPPMAX(g, 0x114);
    g = DPPMAX(g, 0x118);
    float gm = __uint_as_float(__builtin_amdgcn_readlane(__float_as_uint(g), 15));
    int l0 = (int)__builtin_ctzll(__ballot(sv == gm));  // lowest lane = lowest slot
    unsigned gi = (unsigned)__builtin_amdgcn_readlane((int)si, l0);
    if (tid == 0) cIdx[b * SGRP + step] = (int)gi;
    cx = xs[gi]; cy = ys[gi]; cz = zs[gi];   // LDS broadcast
  }
}

// ---------------- kNN v4b: r13's proven structure + precomputed psq -------------
// 512 thr x 16 pts; init loads ps from psq (saves 5 VALU/pt). Selection:
// in-thread cached min -> 6-level DPP prefix-min -> ballot/ctz/readlane
// (+ rare exact-tie index scan) -> per-wave u64-key LDS atomicMin (key embeds
// index: lower index wins) -> 1 barrier/iter. Winner-only rescan.
__global__ __launch_bounds__(512) void knn_kernel(const float* __restrict__ xyz,
                                                  const int* __restrict__ cIdx,
                                                  const float* __restrict__ psq,
                                                  float* __restrict__ nbrDiff,
                                                  float* __restrict__ ctrW,
                                                  float* __restrict__ partials) {
  #pragma clang fp contract(off)
  __shared__ unsigned long long keyBuf[4];
  __shared__ int winners[KNBR];
  const int cid = blockIdx.x;
  const int b = cid >> 9;
  const int tid = threadIdx.x;
  const int lane = tid & 63;
  const float* xb = xyz + (size_t)b * NPTS * 3;
  const float* pq = psq + (size_t)b * NPTS;
  const int cI = cIdx[cid];
  const float cx = xb[cI * 3], cy = xb[cI * 3 + 1], cz = xb[cI * 3 + 2];
  const float cs = (cx * cx + cy * cy) + cz * cz;

  float d2[16];
  float mv = __builtin_inff(); int mi = 0;
  #pragma unroll
  for (int j = 0; j < 16; ++j) {
    int p = tid + (j << 9);
    float x = xb[p * 3], y = xb[p * 3 + 1], z = xb[p * 3 + 2];
    float ps = pq[p];
    float dot = (cx * x + cy * y) + cz * z;
    d2[j] = (cs + ps) - 2.0f * dot;
    if (d2[j] < mv) { mv = d2[j]; mi = p; }   // strict <: lowest p on tie
  }
  if (tid < 4) keyBuf[tid] = 0xFFFFFFFFFFFFFFFFull;
  __syncthreads();

  for (int it = 0; it < KNBR; ++it) {
    if (tid == 0) keyBuf[(it + 2) & 3] = 0xFFFFFFFFFFFFFFFFull;
    float m = mv;
    m = DPPMIN(m, 0x111); m = DPPMIN(m, 0x112); m = DPPMIN(m, 0x114);
    m = DPPMIN(m, 0x118); m = DPPMIN(m, 0x142); m = DPPMIN(m, 0x143);
    float wmin = __uint_as_float(__builtin_amdgcn_readlane(__float_as_uint(m), 63));
    unsigned long long msk = __ballot(mv == wmin);
    int src = (int)__builtin_ctzll(msk);
    int wbi = __builtin_amdgcn_readlane(mi, src);
    if (__builtin_popcountll(msk) > 1) {      // rare exact-tie: min INDEX wins
      unsigned long long rest = msk & (msk - 1);
      while (rest) {
        int l = (int)__builtin_ctzll(rest);
        int cand = __builtin_amdgcn_readlane(mi, l);
        if (cand < wbi) wbi = cand;
        rest &= rest - 1;
      }
    }
    if (lane == 0) {
      unsigned u = __float_as_uint(wmin);
      unsigned mm = u ^ (unsigned)(((int)u >> 31) | 0x80000000);   // monotone float->uint
      unsigned long long key = (((unsigned long long)mm) << 32) | (unsigned long long)(unsigned)wbi;
      atomicMin(&keyBuf[it & 3], key);
    }
    __syncthreads();
    unsigned long long k = keyBuf[it & 3];
    int wi = (int)(k & 0x1FFFu);
    if (tid == 0) winners[it] = wi;
    if (tid == (wi & 511)) {     // only the owner rescans its 16 values
      #pragma unroll
      for (int j = 0; j < 16; ++j)
        if (wi == tid + (j << 9)) d2[j] = __builtin_inff();
      mv = __builtin_inff(); mi = 0;
      #pragma unroll
      for (int j = 0; j < 16; ++j)
        if (d2[j] < mv) { mv = d2[j]; mi = tid + (j << 9); }
    }
  }
  __syncthreads();

  // gather diffs + per-center stats partials
  float sum = 0.f, sq = 0.f;
  if (tid < KNBR) {
    int w = winners[tid];
    float dx = xb[w * 3] - cx, dy = xb[w * 3 + 1] - cy, dz = xb[w * 3 + 2] - cz;
    size_t o = ((size_t)cid * KNBR + tid) * 3;
    nbrDiff[o + 0] = dx; nbrDiff[o + 1] = dy; nbrDiff[o + 2] = dz;
    sum = (dx + dy) + dz;
    sq = (dx * dx + dy * dy) + dz * dz;
  }
  if (tid < 64) {
    #pragma unroll
    for (int s = 1; s < 64; s <<= 1) { sum += __shfl_xor(sum, s); sq += __shfl_xor(sq, s); }
    if (tid == 0) { partials[cid * 2] = sum; partials[cid * 2 + 1] = sq; }
  }
  if (tid < 3) ctrW[(size_t)cid * 3 + tid] = xb[cI * 3 + tid];
}

// ---------------- per-batch std (ddof=1), deterministic fp64 tree ----------------
__global__ __launch_bounds__(256) void std_kernel(const float* __restrict__ partials,
                                                  float* __restrict__ stdv) {
  __shared__ double sd[256], sq[256];
  const int b = blockIdx.x, t = threadIdx.x;
  int i0 = (b * 512 + t) * 2;
  sd[t] = (double)partials[i0] + (double)partials[i0 + 512];
  sq[t] = (double)partials[i0 + 1] + (double)partials[i0 + 513];
  for (int st = 128; st > 0; st >>= 1) {
    __syncthreads();
    if (t < st) { sd[t] += sd[t + st]; sq[t] += sq[t + st]; }
  }
  if (t == 0) {
    double n = (double)(SGRP * KNBR * 3);
    double mean = sd[0] / n;
    double var = (sq[0] - sd[0] * mean) / (n - 1.0);
    stdv[b] = (float)sqrt(var);
  }
}

// ---------------- fused group MLP (t-net + pre res_block + maxpool) ----------------
static __device__ __forceinline__ void gemm_half(const unsigned short* __restrict__ W,
                                                 const unsigned short* ht,
                                                 int oBase, int n0, int r16, int g4,
                                                 f32x4 acc[3][4]) {
  for (int ks = 0; ks < 12; ++ks) {
    const int kOff = ks * 32 + g4 * 8;
    bf16x8 a[3], bb[4];
    #pragma unroll
    for (int i = 0; i < 3; ++i)
      a[i] = *(const bf16x8*)(W + (size_t)(oBase + i * 16 + r16) * CCH + kOff);
    #pragma unroll
    for (int j = 0; j < 4; ++j)
      bb[j] = *(const bf16x8*)(ht + (n0 + j * 16 + r16) * LDSP + kOff);
    #pragma unroll
    for (int i = 0; i < 3; ++i) {
      #pragma unroll
      for (int j = 0; j < 4; ++j)
        acc[i][j] = __builtin_amdgcn_mfma_f32_16x16x32_bf16(a[i], bb[j], acc[i][j], 0, 0, 0);
    }
  }
}

__global__ __launch_bounds__(512) void group_mlp_kernel(
    const float* __restrict__ alpha, const float* __restrict__ beta,
    const float* __restrict__ WtF, const float* __restrict__ btF,
    const unsigned short* __restrict__ W1, const float* __restrict__ b1,
    const unsigned short* __restrict__ W2, const float* __restrict__ b2,
    const float* __restrict__ nbrDiff, const float* __restrict__ ctrW,
    const float* __restrict__ stdv, unsigned short* __restrict__ feat) {
  __shared__ unsigned short ht[128 * LDSP];
  __shared__ float xtw[128 * 8];
  __shared__ float wtl[CCH * 6];
  __shared__ float btl[CCH];

  const int tid = threadIdx.x;
  const int lane = tid & 63, wid = tid >> 6;
  const int r16 = lane & 15, g4 = lane >> 4;
  const int bid = blockIdx.x;
  const int b = bid >> 7;
  const int sBase = (bid & 127) << 2;

  for (int i = tid; i < CCH * 6; i += 512) wtl[i] = WtF[i];
  for (int i = tid; i < CCH; i += 512) btl[i] = btF[i];

  const float inv = 1.0f / (stdv[b] + 1e-5f);
  if (tid < 128) {
    int g = tid >> 5, kk = tid & 31;
    int cid = b * SGRP + sBase + g;
    const float* nb = nbrDiff + ((size_t)cid * KNBR + kk) * 3;
    const float* cc = ctrW + (size_t)cid * 3;
    #pragma unroll
    for (int c = 0; c < 3; ++c) {
      xtw[tid * 8 + c] = alpha[c] * (nb[c] * inv) + beta[c];
      xtw[tid * 8 + 3 + c] = cc[c];
    }
  }
  __syncthreads();

  // conv1 (t-net, K=6) -> h0 bf16 into ht[l][o], 4-wide packed LDS writes
  {
    int l = tid & 127, oi = tid >> 7;
    float xv[6];
    #pragma unroll
    for (int c = 0; c < 6; ++c) xv[c] = xtw[l * 8 + c];
    for (int j4 = 0; j4 < 24; ++j4) {
      int o = oi * 96 + j4 * 4;
      float vv[4];
      #pragma unroll
      for (int r = 0; r < 4; ++r) {
        float v = btl[o + r];
        #pragma unroll
        for (int c = 0; c < 6; ++c) v += wtl[(o + r) * 6 + c] * xv[c];
        vv[r] = fmaxf(v, 0.0f);
      }
      *(uint2*)(ht + l * LDSP + o) = make_uint2(pk2(vv[0], vv[1]), pk2(vv[2], vv[3]));
    }
  }
  __syncthreads();

  const int oBase = wid * 48;

  // conv2: h1 = relu(W1 h0 + b1), overwrite ht by l-halves (disjoint rows)
  for (int half = 0; half < 2; ++half) {
    const int n0 = half * 64;
    f32x4 acc[3][4];
    #pragma unroll
    for (int i = 0; i < 3; ++i) {
      #pragma unroll
      for (int j = 0; j < 4; ++j) acc[i][j] = (f32x4){0.f, 0.f, 0.f, 0.f};
    }
    gemm_half(W1, ht, oBase, n0, r16, g4, acc);
    __syncthreads();   // all waves done reading this half's h0 rows
    #pragma unroll
    for (int i = 0; i < 3; ++i) {
      int o4 = oBase + i * 16 + g4 * 4;
      float bs0 = b1[o4], bs1 = b1[o4 + 1], bs2 = b1[o4 + 2], bs3 = b1[o4 + 3];
      #pragma unroll
      for (int j = 0; j < 4; ++j) {
        int row = n0 + j * 16 + r16;
        unsigned u0 = pk2(fmaxf(acc[i][j][0] + bs0, 0.f), fmaxf(acc[i][j][1] + bs1, 0.f));
        unsigned u1 = pk2(fmaxf(acc[i][j][2] + bs2, 0.f), fmaxf(acc[i][j][3] + bs3, 0.f));
        *(uint2*)(ht + row * LDSP + o4) = make_uint2(u0, u1);
      }
    }
    __syncthreads();
  }

  // conv3 + bias + residual(h0 recomputed) + relu + maxpool over K=32
  for (int half = 0; half < 2; ++half) {
    const int n0 = half * 64;
    f32x4 acc[3][4];
    #pragma unroll
    for (int i = 0; i < 3; ++i) {
      #pragma unroll
      for (int j = 0; j < 4; ++j) acc[i][j] = (f32x4){0.f, 0.f, 0.f, 0.f};
    }
    gemm_half(W2, ht, oBase, n0, r16, g4, acc);

    float bias2[3][4];
    #pragma unroll
    for (int i = 0; i < 3; ++i) {
      int o4 = oBase + i * 16 + g4 * 4;
      #pragma unroll
      for (int r = 0; r < 4; ++r) bias2[i][r] = b2[o4 + r];
    }
    float mx[3][2][4];
    #pragma unroll
    for (int i = 0; i < 3; ++i) {
      #pragma unroll
      for (int gg = 0; gg < 2; ++gg) {
        #pragma unroll
        for (int r = 0; r < 4; ++r) mx[i][gg][r] = 0.f;   // values are relu'd (>=0)
      }
    }
    #pragma unroll
    for (int j = 0; j < 4; ++j) {
      int l = n0 + j * 16 + r16;
      float xv[6];
      #pragma unroll
      for (int c = 0; c < 6; ++c) xv[c] = xtw[l * 8 + c];
      #pragma unroll
      for (int i = 0; i < 3; ++i) {
        int o4 = oBase + i * 16 + g4 * 4;
        #pragma unroll
        for (int r = 0; r < 4; ++r) {
          float h0 = btl[o4 + r];
          #pragma unroll
          for (int c = 0; c < 6; ++c) h0 += wtl[(o4 + r) * 6 + c] * xv[c];
          h0 = fmaxf(h0, 0.f);
          float v = fmaxf(acc[i][j][r] + bias2[i][r] + h0, 0.f);
          mx[i][j >> 1][r] = fmaxf(mx[i][j >> 1][r], v);
        }
      }
    }
    #pragma unroll
    for (int i = 0; i < 3; ++i) {
      #pragma unroll
      for (int gg = 0; gg < 2; ++gg) {
        float m0 = mx[i][gg][0], m1 = mx[i][gg][1], m2 = mx[i][gg][2], m3 = mx[i][gg][3];
        #pragma unroll
        for (int s = 1; s < 16; s <<= 1) {
          m0 = fmaxf(m0, __shfl_xor(m0, s));
          m1 = fmaxf(m1, __shfl_xor(m1, s));
          m2 = fmaxf(m2, __shfl_xor(m2, s));
          m3 = fmaxf(m3, __shfl_xor(m3, s));
        }
        if (r16 == 0) {
          int sIdx = sBase + half * 2 + gg;
          size_t fi = ((size_t)(b * SGRP + sIdx)) * CCH + oBase + i * 16 + g4 * 4;
          *(uint2*)(feat + fi) = make_uint2(pk2(m0, m1), pk2(m2, m3));
        }
      }
    }
  }
}

// ---------------- pos res_block on feat (B,384,512) + final transpose to (B,S,C) fp32 ----------------
__global__ __launch_bounds__(256) void pos_kernel(const unsigned short* __restrict__ feat,
                                                  const unsigned short* __restrict__ Wp1,
                                                  const float* __restrict__ bp1,
                                                  const unsigned short* __restrict__ Wp2,
                                                  const float* __restrict__ bp2,
                                                  float* __restrict__ out) {
  __shared__ unsigned short h1[16 * LDSP];
  const int tid = threadIdx.x;
  const int lane = tid & 63, wid = tid >> 6;
  const int r16 = lane & 15, g4 = lane >> 4;
  const int bid = blockIdx.x;
  const int b = bid >> 5;
  const int s0 = (bid & 31) << 4;
  const size_t rowBase = ((size_t)(b * SGRP + s0 + r16)) * CCH;

  f32x4 acc[6];
  #pragma unroll
  for (int i = 0; i < 6; ++i) acc[i] = (f32x4){0.f, 0.f, 0.f, 0.f};
  for (int ks = 0; ks < 12; ++ks) {
    const int kOff = ks * 32 + g4 * 8;
    bf16x8 bfr = *(const bf16x8*)(feat + rowBase + kOff);
    #pragma unroll
    for (int i = 0; i < 6; ++i) {
      bf16x8 a = *(const bf16x8*)(Wp1 + (size_t)(wid * 96 + i * 16 + r16) * CCH + kOff);
      acc[i] = __builtin_amdgcn_mfma_f32_16x16x32_bf16(a, bfr, acc[i], 0, 0, 0);
    }
  }
  #pragma unroll
  for (int i = 0; i < 6; ++i) {
    int o4 = wid * 96 + i * 16 + g4 * 4;
    unsigned u0 = pk2(fmaxf(acc[i][0] + bp1[o4 + 0], 0.f), fmaxf(acc[i][1] + bp1[o4 + 1], 0.f));
    unsigned u1 = pk2(fmaxf(acc[i][2] + bp1[o4 + 2], 0.f), fmaxf(acc[i][3] + bp1[o4 + 3], 0.f));
    *(uint2*)(h1 + r16 * LDSP + o4) = make_uint2(u0, u1);
  }
  __syncthreads();

  f32x4 acc2[6];
  #pragma unroll
  for (int i = 0; i < 6; ++i) acc2[i] = (f32x4){0.f, 0.f, 0.f, 0.f};
  for (int ks = 0; ks < 12; ++ks) {
    const int kOff = ks * 32 + g4 * 8;
    bf16x8 bfr = *(const bf16x8*)(h1 + r16 * LDSP + kOff);
    #pragma unroll
    for (int i = 0; i < 6; ++i) {
      bf16x8 a = *(const bf16x8*)(Wp2 + (size_t)(wid * 96 + i * 16 + r16) * CCH + kOff);
      acc2[i] = __builtin_amdgcn_mfma_f32_16x16x32_bf16(a, bfr, acc2[i], 0, 0, 0);
    }
  }
  #pragma unroll
  for (int i = 0; i < 6; ++i) {
    int o4 = wid * 96 + i * 16 + g4 * 4;
    uint2 rr = *(const uint2*)(feat + rowBase + o4);
    float4 v;
    v.x = fmaxf(acc2[i][0] + bp2[o4 + 0] + b2f((unsigned short)(rr.x & 0xffff)), 0.f);
    v.y = fmaxf(acc2[i][1] + bp2[o4 + 1] + b2f((unsigned short)(rr.x >> 16)), 0.f);
    v.z = fmaxf(acc2[i][2] + bp2[o4 + 2] + b2f((unsigned short)(rr.y & 0xffff)), 0.f);
    v.w = fmaxf(acc2[i][3] + bp2[o4 + 3] + b2f((unsigned short)(rr.y >> 16)), 0.f);
    *(float4*)(out + rowBase + o4) = v;
  }
}

// ---------------- launch ----------------
extern "C" void kernel_launch(void* const* d_in, const int* in_sizes, int n_in,
                              void* d_out, int out_size, void* d_ws, size_t ws_size,
                              hipStream_t stream) {
  (void)in_sizes; (void)n_in; (void)out_size; (void)ws_size;
  const float* xyz   = (const float*)d_in[0];
  const float* alpha = (const float*)d_in[1];
  const float* beta  = (const float*)d_in[2];
  const float* Wt    = (const float*)d_in[3];
  const float* bt    = (const float*)d_in[4];
  const float* gt    = (const float*)d_in[5];
  const float* bbt   = (const float*)d_in[6];
  const float* Wpre1 = (const float*)d_in[7];
  const float* bpre1 = (const float*)d_in[8];
  const float* gpre1 = (const float*)d_in[9];
  const float* bbpre1= (const float*)d_in[10];
  const float* Wpre2 = (const float*)d_in[11];
  const float* bpre2 = (const float*)d_in[12];
  const float* gpre2 = (const float*)d_in[13];
  const float* bbpre2= (const float*)d_in[14];
  const float* Wpos1 = (const float*)d_in[15];
  const float* bpos1 = (const float*)d_in[16];
  const float* gpos1 = (const float*)d_in[17];
  const float* bbpos1= (const float*)d_in[18];
  const float* Wpos2 = (const float*)d_in[19];
  const float* bpos2 = (const float*)d_in[20];
  const float* gpos2 = (const float*)d_in[21];
  const float* bbpos2= (const float*)d_in[22];

  char* ws = (char*)d_ws;
  size_t off = 0;
  auto alloc = [&](size_t bytes) -> void* {
    void* p = ws + off;
    off += (bytes + 255) & ~(size_t)255;
    return p;
  };
  float* WtF = (float*)alloc(CCH * 6 * 4);
  float* btF = (float*)alloc(CCH * 4);
  unsigned short* W1 = (unsigned short*)alloc(CCH * CCH * 2);
  float* b1 = (float*)alloc(CCH * 4);
  unsigned short* W2 = (unsigned short*)alloc(CCH * CCH * 2);
  float* b2 = (float*)alloc(CCH * 4);
  unsigned short* Wp1 = (unsigned short*)alloc(CCH * CCH * 2);
  float* bp1 = (float*)alloc(CCH * 4);
  unsigned short* Wp2 = (unsigned short*)alloc(CCH * CCH * 2);
  float* bp2 = (float*)alloc(CCH * 4);
  int* cIdx = (int*)alloc(8 * SGRP * 4);
  float* ctrW = (float*)alloc(8 * SGRP * 3 * 4);
  float* nbrD = (float*)alloc((size_t)8 * SGRP * KNBR * 3 * 4);
  float* partials = (float*)alloc(8 * SGRP * 2 * 4);
  float* stdv = (float*)alloc(8 * 4);
  unsigned short* feat = (unsigned short*)alloc((size_t)8 * SGRP * CCH * 2);
  float* psq = (float*)alloc((size_t)8 * NPTS * 4);

  FoldArgs fa0{Wpre1, bpre1, gpre1, bbpre1, W1, b1};
  FoldArgs fa1{Wpre2, bpre2, gpre2, bbpre2, W2, b2};
  FoldArgs fa2{Wpos1, bpos1, gpos1, bbpos1, Wp1, bp1};
  FoldArgs fa3{Wpos2, bpos2, gpos2, bbpos2, Wp2, bp2};

  fps_fold_kernel<<<32, 1024, 0, stream>>>(xyz, cIdx, fa0, fa1, fa2, fa3,
                                           Wt, bt, gt, bbt, WtF, btF, psq);
  knn_kernel<<<8 * SGRP, 512, 0, stream>>>(xyz, cIdx, psq, nbrD, ctrW, partials);
  std_kernel<<<8, 256, 0, stream>>>(partials, stdv);
  group_mlp_kernel<<<1024, 512, 0, stream>>>(alpha, beta, WtF, btF, W1, b1, W2, b2,
                                             nbrD, ctrW, stdv, feat);
  pos_kernel<<<256, 256, 0, stream>>>(feat, Wp1, bp1, Wp2, bp2, (float*)d_out);
}

// Round 17
// 933.245 us; speedup vs baseline: 1.0406x; 1.0406x over previous
//
#include <hip/hip_runtime.h>
#include <hip/hip_bf16.h>
#include <math.h>

typedef __bf16 bf16x8 __attribute__((ext_vector_type(8)));
typedef float f32x4 __attribute__((ext_vector_type(4)));
typedef float f32x2 __attribute__((ext_vector_type(2)));

#define NPTS 8192
#define SGRP 512
#define KNBR 32
#define CCH 384
#define LDSP 392   // padded ushort row stride for [l][c] LDS tiles

static __device__ __forceinline__ unsigned short f2b(float f) {
  union { float f; unsigned u; } v; v.f = f;
  return (unsigned short)((v.u + 0x7fffu + ((v.u >> 16) & 1u)) >> 16);
}
static __device__ __forceinline__ float b2f(unsigned short u) {
  union { unsigned u; float f; } v; v.u = ((unsigned)u) << 16;
  return v.f;
}
static __device__ __forceinline__ unsigned pk2(float a, float b) {
  return (unsigned)f2b(a) | ((unsigned)f2b(b) << 16);
}

// fmax/fmin with DPP-shifted self. Identity for shifted-in lanes:
// max: 0 (distances >= 0); min: +inf.
#define DPPMAX(v, ctrl) \
  fmaxf((v), __int_as_float(__builtin_amdgcn_update_dpp(0, __float_as_int(v), (ctrl), 0xf, 0xf, false)))
#define DPPMIN(v, ctrl) \
  fminf((v), __int_as_float(__builtin_amdgcn_update_dpp(0x7f800000, __float_as_int(v), (ctrl), 0xf, 0xf, false)))

// ---------------- weight folding: bn(conv(x)) = (W*s)x + (b*s+bb) ----------------
struct FoldArgs {
  const float *W, *b, *g, *bb;
  unsigned short* Wd;
  float* bd;
};
__global__ void fold4_bf16(FoldArgs a0, FoldArgs a1, FoldArgs a2, FoldArgs a3) {
  FoldArgs a = (blockIdx.y == 0) ? a0 : (blockIdx.y == 1) ? a1 : (blockIdx.y == 2) ? a2 : a3;
  int o = blockIdx.x;
  float sc = a.g[o] / sqrtf(1.0f + 1e-5f);
  for (int c = threadIdx.x; c < CCH; c += blockDim.x)
    a.Wd[o * CCH + c] = f2b(a.W[o * CCH + c] * sc);
  if (threadIdx.x == 0) a.bd[o] = a.b[o] * sc + a.bb[o];
}
__global__ void fold_w_f32(const float* __restrict__ W, const float* __restrict__ b,
                           const float* __restrict__ g, const float* __restrict__ bb,
                           float* __restrict__ Wd, float* __restrict__ bd, int Cin) {
  int o = blockIdx.x;
  float sc = g[o] / sqrtf(1.0f + 1e-5f);
  for (int c = threadIdx.x; c < Cin; c += blockDim.x)
    Wd[o * Cin + c] = W[o * Cin + c] * sc;
  if (threadIdx.x == 0) bd[o] = b[o] * sc + bb[o];
}

// ---------------- FPS v13 (proven 478us): 1024 thr x 8 pts, packed f32 ----------
// VALU-issue-bound at 4 waves/SIMD. In-thread argmax = value tree-max
// (v_max3-fusable) + descending-j equality scan (lowest j wins on ties).
// 96KB LDS = coord lookup + allocator pin (prevents the 64-VGPR-budget spill
// seen whenever static LDS is small -- DO NOT SHRINK xs/ys/zs). Contiguous
// ownership (tid owns [tid*8, tid*8+8)) + lowest-j/lowest-lane/lowest-slot
// selection everywhere => numpy first-max ties. contract off: ulp-exact dists.
__global__ __launch_bounds__(1024)
void fps_kernel(const float* __restrict__ xyz, int* __restrict__ cIdx) {
  #pragma clang fp contract(off)
  __shared__ float xs[NPTS], ys[NPTS], zs[NPTS];   // 96KB
  __shared__ float slotV[2][16];
  __shared__ unsigned slotI[2][16];
  const int tid = threadIdx.x, lane = tid & 63, wid = tid >> 6;   // wid 0..15
  const int b = blockIdx.x;
  const float* xb = xyz + (size_t)b * NPTS * 3;

  f32x2 X2[4], Y2[4], Z2[4], D2[4];
  {
    const float4* s = (const float4*)xb + tid * 6;
    float4 t0 = s[0], t1 = s[1], t2 = s[2], t3 = s[3], t4 = s[4], t5 = s[5];
    X2[0] = (f32x2){t0.x, t0.w}; Y2[0] = (f32x2){t0.y, t1.x}; Z2[0] = (f32x2){t0.z, t1.y};
    X2[1] = (f32x2){t1.z, t2.y}; Y2[1] = (f32x2){t1.w, t2.z}; Z2[1] = (f32x2){t2.x, t2.w};
    X2[2] = (f32x2){t3.x, t3.w}; Y2[2] = (f32x2){t3.y, t4.x}; Z2[2] = (f32x2){t3.z, t4.y};
    X2[3] = (f32x2){t4.z, t5.y}; Y2[3] = (f32x2){t4.w, t5.z}; Z2[3] = (f32x2){t5.x, t5.w};
  }
  #pragma unroll
  for (int j = 0; j < 4; ++j) {
    int p = tid * 8 + j * 2;
    xs[p] = X2[j].x; ys[p] = Y2[j].x; zs[p] = Z2[j].x;
    xs[p + 1] = X2[j].y; ys[p + 1] = Y2[j].y; zs[p + 1] = Z2[j].y;
    D2[j] = (f32x2){__builtin_inff(), __builtin_inff()};
  }
  if (tid == 0) cIdx[b * SGRP] = 0;
  __syncthreads();
  float cx = xs[0], cy = ys[0], cz = zs[0];
  const int tbase = tid * 8;

  for (int step = 1; step < SGRP; ++step) {
    const int par = step & 1;
    const f32x2 cxv = (f32x2){cx, cx}, cyv = (f32x2){cy, cy}, czv = (f32x2){cz, cz};
    // packed dist update
    #pragma unroll
    for (int j = 0; j < 4; ++j) {
      f32x2 dx = X2[j] - cxv, dy = Y2[j] - cyv, dz = Z2[j] - czv;
      f32x2 d = (dx * dx + dy * dy) + dz * dz;   // contract off: numpy ulp-exact
      D2[j] = __builtin_elementwise_min(D2[j], d);
    }
    // value tree-max (v_max3-fusable triples), then index by equality scan
    float bv;
    {
      float a = fmaxf(fmaxf(D2[0].x, D2[0].y), D2[1].x);
      float c = fmaxf(fmaxf(D2[1].y, D2[2].x), D2[2].y);
      float e = fmaxf(fmaxf(D2[3].x, D2[3].y), a);
      bv = fmaxf(c, e);
    }
    int bi = tbase + 7;                          // descending j: lowest j wins
    bi = (D2[3].x == bv) ? tbase + 6 : bi;
    bi = (D2[2].y == bv) ? tbase + 5 : bi;
    bi = (D2[2].x == bv) ? tbase + 4 : bi;
    bi = (D2[1].y == bv) ? tbase + 3 : bi;
    bi = (D2[1].x == bv) ? tbase + 2 : bi;
    bi = (D2[0].y == bv) ? tbase + 1 : bi;
    bi = (D2[0].x == bv) ? tbase + 0 : bi;
    // wave max (value only), pure VALU
    float m = bv;
    m = DPPMAX(m, 0x111); m = DPPMAX(m, 0x112); m = DPPMAX(m, 0x114);
    m = DPPMAX(m, 0x118); m = DPPMAX(m, 0x142); m = DPPMAX(m, 0x143);
    float wmax = __uint_as_float(__builtin_amdgcn_readlane(__float_as_uint(m), 63));
    unsigned long long msk = __ballot(bv == wmax);
    int srcLane = (int)__builtin_ctzll(msk);          // lowest lane == lowest index
    unsigned wbi = (unsigned)__builtin_amdgcn_readlane(bi, srcLane);
    if (lane == 0) { slotV[par][wid] = wmax; slotI[par][wid] = wbi; }
    __syncthreads();   // the only barrier per step
    // in-register 16-slot combine: lane l holds slot l&15 (broadcast reads)
    float sv = slotV[par][lane & 15];
    unsigned si = slotI[par][lane & 15];
    float g = sv;
    g = DPPMAX(g, 0x111); g = DPPMAX(g, 0x112); g = DPPMAX(g, 0x114);
    g = DPPMAX(g, 0x118);
    float gm = __uint_as_float(__builtin_amdgcn_readlane(__float_as_uint(g), 15));
    int l0 = (int)__builtin_ctzll(__ballot(sv == gm));  // lowest lane = lowest slot
    unsigned gi = (unsigned)__builtin_amdgcn_readlane((int)si, l0);
    if (tid == 0) cIdx[b * SGRP + step] = (int)gi;
    cx = xs[gi]; cy = ys[gi]; cz = zs[gi];   // LDS broadcast
  }
}

// ---------------- kNN v4 (proven): 512 thr x 16 pts, DPP value-min reduce -------
// Selection: in-thread cached min -> 6-level DPP prefix-min -> ballot/ctz/
// readlane (+ rare exact-tie index scan) -> per-wave u64-key LDS atomicMin
// (key embeds index: lower index wins) -> 1 barrier/iter. Winner-only rescan.
// |p|^2 recomputed in-register (r16 lesson: precomputed psq costs more in L2
// traffic than it saves in VALU).
__global__ __launch_bounds__(512) void knn_kernel(const float* __restrict__ xyz,
                                                  const int* __restrict__ cIdx,
                                                  float* __restrict__ nbrDiff,
                                                  float* __restrict__ ctrW,
                                                  float* __restrict__ partials) {
  #pragma clang fp contract(off)
  __shared__ unsigned long long keyBuf[4];
  __shared__ int winners[KNBR];
  const int cid = blockIdx.x;
  const int b = cid >> 9;
  const int tid = threadIdx.x;
  const int lane = tid & 63;
  const float* xb = xyz + (size_t)b * NPTS * 3;
  const int cI = cIdx[cid];
  const float cx = xb[cI * 3], cy = xb[cI * 3 + 1], cz = xb[cI * 3 + 2];
  const float cs = (cx * cx + cy * cy) + cz * cz;

  float d2[16];
  float mv = __builtin_inff(); int mi = 0;
  #pragma unroll
  for (int j = 0; j < 16; ++j) {
    int p = tid + (j << 9);
    float x = xb[p * 3], y = xb[p * 3 + 1], z = xb[p * 3 + 2];
    float ps = (x * x + y * y) + z * z;
    float dot = (cx * x + cy * y) + cz * z;
    d2[j] = (cs + ps) - 2.0f * dot;
    if (d2[j] < mv) { mv = d2[j]; mi = p; }   // strict <: lowest p on tie
  }
  if (tid < 4) keyBuf[tid] = 0xFFFFFFFFFFFFFFFFull;
  __syncthreads();

  for (int it = 0; it < KNBR; ++it) {
    if (tid == 0) keyBuf[(it + 2) & 3] = 0xFFFFFFFFFFFFFFFFull;
    float m = mv;
    m = DPPMIN(m, 0x111); m = DPPMIN(m, 0x112); m = DPPMIN(m, 0x114);
    m = DPPMIN(m, 0x118); m = DPPMIN(m, 0x142); m = DPPMIN(m, 0x143);
    float wmin = __uint_as_float(__builtin_amdgcn_readlane(__float_as_uint(m), 63));
    unsigned long long msk = __ballot(mv == wmin);
    int src = (int)__builtin_ctzll(msk);
    int wbi = __builtin_amdgcn_readlane(mi, src);
    if (__builtin_popcountll(msk) > 1) {      // rare exact-tie: min INDEX wins
      unsigned long long rest = msk & (msk - 1);
      while (rest) {
        int l = (int)__builtin_ctzll(rest);
        int cand = __builtin_amdgcn_readlane(mi, l);
        if (cand < wbi) wbi = cand;
        rest &= rest - 1;
      }
    }
    if (lane == 0) {
      unsigned u = __float_as_uint(wmin);
      unsigned mm = u ^ (unsigned)(((int)u >> 31) | 0x80000000);   // monotone float->uint
      unsigned long long key = (((unsigned long long)mm) << 32) | (unsigned long long)(unsigned)wbi;
      atomicMin(&keyBuf[it & 3], key);
    }
    __syncthreads();
    unsigned long long k = keyBuf[it & 3];
    int wi = (int)(k & 0x1FFFu);
    if (tid == 0) winners[it] = wi;
    if (tid == (wi & 511)) {     // only the owner rescans its 16 values
      #pragma unroll
      for (int j = 0; j < 16; ++j)
        if (wi == tid + (j << 9)) d2[j] = __builtin_inff();
      mv = __builtin_inff(); mi = 0;
      #pragma unroll
      for (int j = 0; j < 16; ++j)
        if (d2[j] < mv) { mv = d2[j]; mi = tid + (j << 9); }
    }
  }
  __syncthreads();

  // gather diffs + per-center stats partials
  float sum = 0.f, sq = 0.f;
  if (tid < KNBR) {
    int w = winners[tid];
    float dx = xb[w * 3] - cx, dy = xb[w * 3 + 1] - cy, dz = xb[w * 3 + 2] - cz;
    size_t o = ((size_t)cid * KNBR + tid) * 3;
    nbrDiff[o + 0] = dx; nbrDiff[o + 1] = dy; nbrDiff[o + 2] = dz;
    sum = (dx + dy) + dz;
    sq = (dx * dx + dy * dy) + dz * dz;
  }
  if (tid < 64) {
    #pragma unroll
    for (int s = 1; s < 64; s <<= 1) { sum += __shfl_xor(sum, s); sq += __shfl_xor(sq, s); }
    if (tid == 0) { partials[cid * 2] = sum; partials[cid * 2 + 1] = sq; }
  }
  if (tid < 3) ctrW[(size_t)cid * 3 + tid] = xb[cI * 3 + tid];
}

// ---------------- per-batch std (ddof=1), deterministic fp64 tree ----------------
__global__ __launch_bounds__(256) void std_kernel(const float* __restrict__ partials,
                                                  float* __restrict__ stdv) {
  __shared__ double sd[256], sq[256];
  const int b = blockIdx.x, t = threadIdx.x;
  int i0 = (b * 512 + t) * 2;
  sd[t] = (double)partials[i0] + (double)partials[i0 + 512];
  sq[t] = (double)partials[i0 + 1] + (double)partials[i0 + 513];
  for (int st = 128; st > 0; st >>= 1) {
    __syncthreads();
    if (t < st) { sd[t] += sd[t + st]; sq[t] += sq[t + st]; }
  }
  if (t == 0) {
    double n = (double)(SGRP * KNBR * 3);
    double mean = sd[0] / n;
    double var = (sq[0] - sd[0] * mean) / (n - 1.0);
    stdv[b] = (float)sqrt(var);
  }
}

// ---------------- fused group MLP (t-net + pre res_block + maxpool) ----------------
static __device__ __forceinline__ void gemm_half(const unsigned short* __restrict__ W,
                                                 const unsigned short* ht,
                                                 int oBase, int n0, int r16, int g4,
                                                 f32x4 acc[3][4]) {
  for (int ks = 0; ks < 12; ++ks) {
    const int kOff = ks * 32 + g4 * 8;
    bf16x8 a[3], bb[4];
    #pragma unroll
    for (int i = 0; i < 3; ++i)
      a[i] = *(const bf16x8*)(W + (size_t)(oBase + i * 16 + r16) * CCH + kOff);
    #pragma unroll
    for (int j = 0; j < 4; ++j)
      bb[j] = *(const bf16x8*)(ht + (n0 + j * 16 + r16) * LDSP + kOff);
    #pragma unroll
    for (int i = 0; i < 3; ++i) {
      #pragma unroll
      for (int j = 0; j < 4; ++j)
        acc[i][j] = __builtin_amdgcn_mfma_f32_16x16x32_bf16(a[i], bb[j], acc[i][j], 0, 0, 0);
    }
  }
}

__global__ __launch_bounds__(512) void group_mlp_kernel(
    const float* __restrict__ alpha, const float* __restrict__ beta,
    const float* __restrict__ WtF, const float* __restrict__ btF,
    const unsigned short* __restrict__ W1, const float* __restrict__ b1,
    const unsigned short* __restrict__ W2, const float* __restrict__ b2,
    const float* __restrict__ nbrDiff, const float* __restrict__ ctrW,
    const float* __restrict__ stdv, unsigned short* __restrict__ feat) {
  __shared__ unsigned short ht[128 * LDSP];
  __shared__ float xtw[128 * 8];
  __shared__ float wtl[CCH * 6];
  __shared__ float btl[CCH];

  const int tid = threadIdx.x;
  const int lane = tid & 63, wid = tid >> 6;
  const int r16 = lane & 15, g4 = lane >> 4;
  const int bid = blockIdx.x;
  const int b = bid >> 7;
  const int sBase = (bid & 127) << 2;

  for (int i = tid; i < CCH * 6; i += 512) wtl[i] = WtF[i];
  for (int i = tid; i < CCH; i += 512) btl[i] = btF[i];

  const float inv = 1.0f / (stdv[b] + 1e-5f);
  if (tid < 128) {
    int g = tid >> 5, kk = tid & 31;
    int cid = b * SGRP + sBase + g;
    const float* nb = nbrDiff + ((size_t)cid * KNBR + kk) * 3;
    const float* cc = ctrW + (size_t)cid * 3;
    #pragma unroll
    for (int c = 0; c < 3; ++c) {
      xtw[tid * 8 + c] = alpha[c] * (nb[c] * inv) + beta[c];
      xtw[tid * 8 + 3 + c] = cc[c];
    }
  }
  __syncthreads();

  // conv1 (t-net, K=6) -> h0 bf16 into ht[l][o], 4-wide packed LDS writes
  {
    int l = tid & 127, oi = tid >> 7;
    float xv[6];
    #pragma unroll
    for (int c = 0; c < 6; ++c) xv[c] = xtw[l * 8 + c];
    for (int j4 = 0; j4 < 24; ++j4) {
      int o = oi * 96 + j4 * 4;
      float vv[4];
      #pragma unroll
      for (int r = 0; r < 4; ++r) {
        float v = btl[o + r];
        #pragma unroll
        for (int c = 0; c < 6; ++c) v += wtl[(o + r) * 6 + c] * xv[c];
        vv[r] = fmaxf(v, 0.0f);
      }
      *(uint2*)(ht + l * LDSP + o) = make_uint2(pk2(vv[0], vv[1]), pk2(vv[2], vv[3]));
    }
  }
  __syncthreads();

  const int oBase = wid * 48;

  // conv2: h1 = relu(W1 h0 + b1), overwrite ht by l-halves (disjoint rows)
  for (int half = 0; half < 2; ++half) {
    const int n0 = half * 64;
    f32x4 acc[3][4];
    #pragma unroll
    for (int i = 0; i < 3; ++i) {
      #pragma unroll
      for (int j = 0; j < 4; ++j) acc[i][j] = (f32x4){0.f, 0.f, 0.f, 0.f};
    }
    gemm_half(W1, ht, oBase, n0, r16, g4, acc);
    __syncthreads();   // all waves done reading this half's h0 rows
    #pragma unroll
    for (int i = 0; i < 3; ++i) {
      int o4 = oBase + i * 16 + g4 * 4;
      float bs0 = b1[o4], bs1 = b1[o4 + 1], bs2 = b1[o4 + 2], bs3 = b1[o4 + 3];
      #pragma unroll
      for (int j = 0; j < 4; ++j) {
        int row = n0 + j * 16 + r16;
        unsigned u0 = pk2(fmaxf(acc[i][j][0] + bs0, 0.f), fmaxf(acc[i][j][1] + bs1, 0.f));
        unsigned u1 = pk2(fmaxf(acc[i][j][2] + bs2, 0.f), fmaxf(acc[i][j][3] + bs3, 0.f));
        *(uint2*)(ht + row * LDSP + o4) = make_uint2(u0, u1);
      }
    }
    __syncthreads();
  }

  // conv3 + bias + residual(h0 recomputed) + relu + maxpool over K=32
  for (int half = 0; half < 2; ++half) {
    const int n0 = half * 64;
    f32x4 acc[3][4];
    #pragma unroll
    for (int i = 0; i < 3; ++i) {
      #pragma unroll
      for (int j = 0; j < 4; ++j) acc[i][j] = (f32x4){0.f, 0.f, 0.f, 0.f};
    }
    gemm_half(W2, ht, oBase, n0, r16, g4, acc);

    float bias2[3][4];
    #pragma unroll
    for (int i = 0; i < 3; ++i) {
      int o4 = oBase + i * 16 + g4 * 4;
      #pragma unroll
      for (int r = 0; r < 4; ++r) bias2[i][r] = b2[o4 + r];
    }
    float mx[3][2][4];
    #pragma unroll
    for (int i = 0; i < 3; ++i) {
      #pragma unroll
      for (int gg = 0; gg < 2; ++gg) {
        #pragma unroll
        for (int r = 0; r < 4; ++r) mx[i][gg][r] = 0.f;   // values are relu'd (>=0)
      }
    }
    #pragma unroll
    for (int j = 0; j < 4; ++j) {
      int l = n0 + j * 16 + r16;
      float xv[6];
      #pragma unroll
      for (int c = 0; c < 6; ++c) xv[c] = xtw[l * 8 + c];
      #pragma unroll
      for (int i = 0; i < 3; ++i) {
        int o4 = oBase + i * 16 + g4 * 4;
        #pragma unroll
        for (int r = 0; r < 4; ++r) {
          float h0 = btl[o4 + r];
          #pragma unroll
          for (int c = 0; c < 6; ++c) h0 += wtl[(o4 + r) * 6 + c] * xv[c];
          h0 = fmaxf(h0, 0.f);
          float v = fmaxf(acc[i][j][r] + bias2[i][r] + h0, 0.f);
          mx[i][j >> 1][r] = fmaxf(mx[i][j >> 1][r], v);
        }
      }
    }
    #pragma unroll
    for (int i = 0; i < 3; ++i) {
      #pragma unroll
      for (int gg = 0; gg < 2; ++gg) {
        float m0 = mx[i][gg][0], m1 = mx[i][gg][1], m2 = mx[i][gg][2], m3 = mx[i][gg][3];
        #pragma unroll
        for (int s = 1; s < 16; s <<= 1) {
          m0 = fmaxf(m0, __shfl_xor(m0, s));
          m1 = fmaxf(m1, __shfl_xor(m1, s));
          m2 = fmaxf(m2, __shfl_xor(m2, s));
          m3 = fmaxf(m3, __shfl_xor(m3, s));
        }
        if (r16 == 0) {
          int sIdx = sBase + half * 2 + gg;
          size_t fi = ((size_t)(b * SGRP + sIdx)) * CCH + oBase + i * 16 + g4 * 4;
          *(uint2*)(feat + fi) = make_uint2(pk2(m0, m1), pk2(m2, m3));
        }
      }
    }
  }
}

// ---------------- pos res_block on feat (B,384,512) + final transpose to (B,S,C) fp32 ----------------
__global__ __launch_bounds__(256) void pos_kernel(const unsigned short* __restrict__ feat,
                                                  const unsigned short* __restrict__ Wp1,
                                                  const float* __restrict__ bp1,
                                                  const unsigned short* __restrict__ Wp2,
                                                  const float* __restrict__ bp2,
                                                  float* __restrict__ out) {
  __shared__ unsigned short h1[16 * LDSP];
  const int tid = threadIdx.x;
  const int lane = tid & 63, wid = tid >> 6;
  const int r16 = lane & 15, g4 = lane >> 4;
  const int bid = blockIdx.x;
  const int b = bid >> 5;
  const int s0 = (bid & 31) << 4;
  const size_t rowBase = ((size_t)(b * SGRP + s0 + r16)) * CCH;

  f32x4 acc[6];
  #pragma unroll
  for (int i = 0; i < 6; ++i) acc[i] = (f32x4){0.f, 0.f, 0.f, 0.f};
  for (int ks = 0; ks < 12; ++ks) {
    const int kOff = ks * 32 + g4 * 8;
    bf16x8 bfr = *(const bf16x8*)(feat + rowBase + kOff);
    #pragma unroll
    for (int i = 0; i < 6; ++i) {
      bf16x8 a = *(const bf16x8*)(Wp1 + (size_t)(wid * 96 + i * 16 + r16) * CCH + kOff);
      acc[i] = __builtin_amdgcn_mfma_f32_16x16x32_bf16(a, bfr, acc[i], 0, 0, 0);
    }
  }
  #pragma unroll
  for (int i = 0; i < 6; ++i) {
    int o4 = wid * 96 + i * 16 + g4 * 4;
    unsigned u0 = pk2(fmaxf(acc[i][0] + bp1[o4 + 0], 0.f), fmaxf(acc[i][1] + bp1[o4 + 1], 0.f));
    unsigned u1 = pk2(fmaxf(acc[i][2] + bp1[o4 + 2], 0.f), fmaxf(acc[i][3] + bp1[o4 + 3], 0.f));
    *(uint2*)(h1 + r16 * LDSP + o4) = make_uint2(u0, u1);
  }
  __syncthreads();

  f32x4 acc2[6];
  #pragma unroll
  for (int i = 0; i < 6; ++i) acc2[i] = (f32x4){0.f, 0.f, 0.f, 0.f};
  for (int ks = 0; ks < 12; ++ks) {
    const int kOff = ks * 32 + g4 * 8;
    bf16x8 bfr = *(const bf16x8*)(h1 + r16 * LDSP + kOff);
    #pragma unroll
    for (int i = 0; i < 6; ++i) {
      bf16x8 a = *(const bf16x8*)(Wp2 + (size_t)(wid * 96 + i * 16 + r16) * CCH + kOff);
      acc2[i] = __builtin_amdgcn_mfma_f32_16x16x32_bf16(a, bfr, acc2[i], 0, 0, 0);
    }
  }
  #pragma unroll
  for (int i = 0; i < 6; ++i) {
    int o4 = wid * 96 + i * 16 + g4 * 4;
    uint2 rr = *(const uint2*)(feat + rowBase + o4);
    float4 v;
    v.x = fmaxf(acc2[i][0] + bp2[o4 + 0] + b2f((unsigned short)(rr.x & 0xffff)), 0.f);
    v.y = fmaxf(acc2[i][1] + bp2[o4 + 1] + b2f((unsigned short)(rr.x >> 16)), 0.f);
    v.z = fmaxf(acc2[i][2] + bp2[o4 + 2] + b2f((unsigned short)(rr.y & 0xffff)), 0.f);
    v.w = fmaxf(acc2[i][3] + bp2[o4 + 3] + b2f((unsigned short)(rr.y >> 16)), 0.f);
    *(float4*)(out + rowBase + o4) = v;
  }
}

// ---------------- launch ----------------
extern "C" void kernel_launch(void* const* d_in, const int* in_sizes, int n_in,
                              void* d_out, int out_size, void* d_ws, size_t ws_size,
                              hipStream_t stream) {
  (void)in_sizes; (void)n_in; (void)out_size; (void)ws_size;
  const float* xyz   = (const float*)d_in[0];
  const float* alpha = (const float*)d_in[1];
  const float* beta  = (const float*)d_in[2];
  const float* Wt    = (const float*)d_in[3];
  const float* bt    = (const float*)d_in[4];
  const float* gt    = (const float*)d_in[5];
  const float* bbt   = (const float*)d_in[6];
  const float* Wpre1 = (const float*)d_in[7];
  const float* bpre1 = (const float*)d_in[8];
  const float* gpre1 = (const float*)d_in[9];
  const float* bbpre1= (const float*)d_in[10];
  const float* Wpre2 = (const float*)d_in[11];
  const float* bpre2 = (const float*)d_in[12];
  const float* gpre2 = (const float*)d_in[13];
  const float* bbpre2= (const float*)d_in[14];
  const float* Wpos1 = (const float*)d_in[15];
  const float* bpos1 = (const float*)d_in[16];
  const float* gpos1 = (const float*)d_in[17];
  const float* bbpos1= (const float*)d_in[18];
  const float* Wpos2 = (const float*)d_in[19];
  const float* bpos2 = (const float*)d_in[20];
  const float* gpos2 = (const float*)d_in[21];
  const float* bbpos2= (const float*)d_in[22];

  char* ws = (char*)d_ws;
  size_t off = 0;
  auto alloc = [&](size_t bytes) -> void* {
    void* p = ws + off;
    off += (bytes + 255) & ~(size_t)255;
    return p;
  };
  float* WtF = (float*)alloc(CCH * 6 * 4);
  float* btF = (float*)alloc(CCH * 4);
  unsigned short* W1 = (unsigned short*)alloc(CCH * CCH * 2);
  float* b1 = (float*)alloc(CCH * 4);
  unsigned short* W2 = (unsigned short*)alloc(CCH * CCH * 2);
  float* b2 = (float*)alloc(CCH * 4);
  unsigned short* Wp1 = (unsigned short*)alloc(CCH * CCH * 2);
  float* bp1 = (float*)alloc(CCH * 4);
  unsigned short* Wp2 = (unsigned short*)alloc(CCH * CCH * 2);
  float* bp2 = (float*)alloc(CCH * 4);
  int* cIdx = (int*)alloc(8 * SGRP * 4);
  float* ctrW = (float*)alloc(8 * SGRP * 3 * 4);
  float* nbrD = (float*)alloc((size_t)8 * SGRP * KNBR * 3 * 4);
  float* partials = (float*)alloc(8 * SGRP * 2 * 4);
  float* stdv = (float*)alloc(8 * 4);
  unsigned short* feat = (unsigned short*)alloc((size_t)8 * SGRP * CCH * 2);

  fold_w_f32<<<CCH, 64, 0, stream>>>(Wt, bt, gt, bbt, WtF, btF, 6);
  FoldArgs fa0{Wpre1, bpre1, gpre1, bbpre1, W1, b1};
  FoldArgs fa1{Wpre2, bpre2, gpre2, bbpre2, W2, b2};
  FoldArgs fa2{Wpos1, bpos1, gpos1, bbpos1, Wp1, bp1};
  FoldArgs fa3{Wpos2, bpos2, gpos2, bbpos2, Wp2, bp2};
  fold4_bf16<<<dim3(CCH, 4), 128, 0, stream>>>(fa0, fa1, fa2, fa3);

  fps_kernel<<<8, 1024, 0, stream>>>(xyz, cIdx);
  knn_kernel<<<8 * SGRP, 512, 0, stream>>>(xyz, cIdx, nbrD, ctrW, partials);
  std_kernel<<<8, 256, 0, stream>>>(partials, stdv);
  group_mlp_kernel<<<1024, 512, 0, stream>>>(alpha, beta, WtF, btF, W1, b1, W2, b2,
                                             nbrD, ctrW, stdv, feat);
  pos_kernel<<<256, 256, 0, stream>>>(feat, Wp1, bp1, Wp2, bp2, (float*)d_out);
}